// Round 9
// baseline (203.454 us; speedup 1.0000x reference)
//
#include <hip/hip_runtime.h>
#include <hip/hip_bf16.h>
#include <cstddef>
#include <cstdint>

// GINConvFFT round 9: barrier-free K-loops with direct-from-global MFMA
// fragment loads (no LDS staging in the hot loops).
//   prep2: MallC even col-slices = (1+eps)I+A_s; MT; Wt          (1280 blk)
//   zmsq : blocks 0-511: Z[(b*64+o)][k*512+m] = Wt[k*64+o][:] . x[b*512+m][:]
//          (x read fp32 directly, cvt in VGPR; reg-pipelined; no barriers)
//          blocks 512-543: MallC odd slices = M_s^2 (LDS form, concurrent)
//   ysum : Yh[kq][r][o] = quarter-K partial of G . Z^T  (512 blk, barrier-free)
//   bn_part/bn_final/bn_out: BN stats over sum of 4 Yh quarters, then
//          normalize+relu+w2+b2.
#define B_   32
#define N_   512
#define D_   768
#define OUT_ 64
#define R_   (B_ * N_)

typedef unsigned short u16;
typedef __bf16 bf16x8 __attribute__((ext_vector_type(8)));
typedef float  f32x4  __attribute__((ext_vector_type(4)));
typedef unsigned short u16x8 __attribute__((ext_vector_type(8)));

__device__ __forceinline__ u16 f2bf(float f) {
    __hip_bfloat16 h = __float2bfloat16(f);
    return __builtin_bit_cast(u16, h);
}

__device__ __forceinline__ f32x4 mfma16(u16x8 a, u16x8 b, f32x4 c) {
    return __builtin_amdgcn_mfma_f32_16x16x32_bf16(
        __builtin_bit_cast(bf16x8, a), __builtin_bit_cast(bf16x8, b), c, 0, 0, 0);
}

// async global->LDS (msq path only)
__device__ __forceinline__ void gl2lds16(const void* g, void* l) {
    __builtin_amdgcn_global_load_lds(
        (const __attribute__((address_space(1))) unsigned int*)g,
        (__attribute__((address_space(3))) unsigned int*)l, 16, 0, 0);
}

// ---------------------------------------------------------------------------
// prep2: [0,512) build M (even MallC col slices) + MT | [512,1280) build Wt
// ---------------------------------------------------------------------------
__global__ __launch_bounds__(256) void prep2(
    const float* __restrict__ support, const float* __restrict__ weight,
    const float* __restrict__ epsp,
    u16* __restrict__ MallC, u16* __restrict__ MT, u16* __restrict__ Wt)
{
    const int blk = blockIdx.x, tid = threadIdx.x;
    __shared__ float t[32][33];
    if (blk < 512) {
        int s = blk >> 8, rem = blk & 255;
        int n0 = (rem >> 4) * 32, m0 = (rem & 15) * 32;
        const float f = 1.0f + epsp[0];
        const float* S = support + (size_t)s * 262144;
#pragma unroll
        for (int p = 0; p < 4; ++p) {
            int nl = p * 8 + (tid >> 5), ml = tid & 31;
            float v = S[(size_t)(n0 + nl) * 512 + m0 + ml];
            if (n0 + nl == m0 + ml) v += f;
            MallC[(size_t)(n0 + nl) * 2048 + s * 1024 + m0 + ml] = f2bf(v);
            t[nl][ml] = v;
        }
        __syncthreads();
#pragma unroll
        for (int p = 0; p < 4; ++p) {
            int ml = p * 8 + (tid >> 5), nl = tid & 31;
            MT[(size_t)s * 262144 + (size_t)(m0 + ml) * 512 + n0 + nl] = f2bf(t[nl][ml]);
        }
    } else {
        int idx = (blk - 512) * 256 + tid;          // 4*64*768 = 196608
        int k = idx / 49152, rem = idx % 49152;
        int o = rem / 768, d = rem % 768;
        int l = d >> 6, hh = d & 63;
        Wt[idx] = f2bf(weight[((size_t)l * 256 + hh * 4 + k) * 64 + o]);
    }
}

// ---------------------------------------------------------------------------
// zmsq:
//  blocks 0-511: barrier-free zgemm. bid -> y = bid&1 (Wt 128-row half),
//    mt = bid>>1 (64-m tile): b = mt>>3, m0 = (mt&7)*64.
//    Waves 2x2: wr = o-64-half within y, wc = m-32-half. Wave tile 64o x 32m.
//    K=768, 24 steps of BK=32, 1-step register pipeline, direct global loads.
//  blocks 512-543: msq 128x128, K=512, BK=64, LDS single-buffered.
// ---------------------------------------------------------------------------
__global__ __launch_bounds__(256) void zmsq(
    const u16* __restrict__ Wt, const float* __restrict__ x,
    const u16* __restrict__ MallC_in, const u16* __restrict__ MT,
    u16* __restrict__ Z, u16* __restrict__ MallC_out)
{
    __shared__ __align__(16) char smem[32768];
    const int tid = threadIdx.x, lane = tid & 63, wid = tid >> 6;
    const int lrow = lane & 15, lk8 = (lane >> 4) * 8;
    const int q = lane >> 4;
    const int bid = blockIdx.x;

    if (bid < 512) {
        const int y = bid & 1, mt = bid >> 1;
        const int b = mt >> 3, m0 = (mt & 7) * 64;
        const int wr = wid >> 1, wc = wid & 1;

        const u16* ap[4];
#pragma unroll
        for (int fi = 0; fi < 4; ++fi)
            ap[fi] = Wt + (size_t)(y * 128 + wr * 64 + fi * 16 + lrow) * 768 + lk8;
        const float* bp[2];
#pragma unroll
        for (int fj = 0; fj < 2; ++fj)
            bp[fj] = x + (size_t)(b * 512 + m0 + wc * 32 + fj * 16 + lrow) * 768 + lk8;

        // prologue: step-0 fragments
        u16x8 Ar[4]; f32x4 Br0[2], Br1[2];
#pragma unroll
        for (int fi = 0; fi < 4; ++fi) Ar[fi] = *(const u16x8*)(ap[fi]);
#pragma unroll
        for (int fj = 0; fj < 2; ++fj) {
            Br0[fj] = *(const f32x4*)(bp[fj]);
            Br1[fj] = *(const f32x4*)(bp[fj] + 4);
        }

        f32x4 acc[4][2] = {};
#pragma unroll
        for (int kk = 0; kk < 24; ++kk) {
            // convert current B (loaded last iter) to bf16
            u16x8 Bc[2];
#pragma unroll
            for (int fj = 0; fj < 2; ++fj) {
                u16x8 w;
#pragma unroll
                for (int j = 0; j < 4; ++j) { w[j] = f2bf(Br0[fj][j]); w[4 + j] = f2bf(Br1[fj][j]); }
                Bc[fj] = w;
            }
            u16x8 Ac[4];
#pragma unroll
            for (int fi = 0; fi < 4; ++fi) Ac[fi] = Ar[fi];
            // issue next step's loads (no barrier, no LDS)
            if (kk < 23) {
                const int d = (kk + 1) * 32;
#pragma unroll
                for (int fi = 0; fi < 4; ++fi) Ar[fi] = *(const u16x8*)(ap[fi] + d);
#pragma unroll
                for (int fj = 0; fj < 2; ++fj) {
                    Br0[fj] = *(const f32x4*)(bp[fj] + d);
                    Br1[fj] = *(const f32x4*)(bp[fj] + d + 4);
                }
            }
#pragma unroll
            for (int fi = 0; fi < 4; ++fi)
#pragma unroll
                for (int fj = 0; fj < 2; ++fj)
                    acc[fi][fj] = mfma16(Ac[fi], Bc[fj], acc[fi][fj]);
        }
        // epilogue: per-wave LDS repack 64(o) x 32(m), stride 40 u16
        u16* Rw = (u16*)smem + wid * 2560;
#pragma unroll
        for (int fi = 0; fi < 4; ++fi)
#pragma unroll
            for (int fj = 0; fj < 2; ++fj)
#pragma unroll
                for (int r = 0; r < 4; ++r)
                    Rw[(fi * 16 + q * 4 + r) * 40 + fj * 16 + lrow] = f2bf(acc[fi][fj][r]);
        __syncthreads();
        const int k = y * 2 + wr;
#pragma unroll
        for (int p = 0; p < 4; ++p) {
            int row = p * 16 + (lane >> 2);          // o
            int cc = (lane & 3) * 8;                 // m chunk
            u16x8 v = *(const u16x8*)(Rw + row * 40 + cc);
            *(u16x8*)(Z + (size_t)(b * 64 + row) * 2048 + k * 512 + m0 + wc * 32 + cc) = v;
        }
    } else {
        // msq: 128x128, K=512, BK=64, LDS single-buffered (32 blocks)
        u16* St = (u16*)smem;
        const int wr = wid >> 1, wc = wid & 1;
        int lb = bid - 512;
        int s = lb >> 4, rem = lb & 15;
        int i0 = (rem >> 2) * 128, j0 = (rem & 3) * 128;
        const u16* Ab = MallC_in + s * 1024;         // stride 2048
        const u16* Bb = MT + (size_t)s * 262144;     // stride 512

        const u16* gsrc[8]; u16* ldst[8];
#pragma unroll
        for (int t = 0; t < 8; ++t) {
            int idx = wid * 8 + t;
            int pan = idx >> 4, q2 = idx & 15;
            if (q2 < 8) {
                gsrc[t] = Ab + (size_t)(i0 + q2 * 16 + lrow) * 2048 + pan * 32 + lk8;
                ldst[t] = St + pan * 8192 + q2 * 512;
            } else {
                gsrc[t] = Bb + (size_t)(j0 + (q2 - 8) * 16 + lrow) * 512 + pan * 32 + lk8;
                ldst[t] = St + pan * 8192 + 4096 + (q2 - 8) * 512;
            }
        }
        f32x4 acc[4][4] = {};
        for (int kk = 0; kk < 8; ++kk) {
#pragma unroll
            for (int t = 0; t < 8; ++t) gl2lds16(gsrc[t], ldst[t]);
#pragma unroll
            for (int t = 0; t < 8; ++t) gsrc[t] += 64;
            __syncthreads();
#pragma unroll
            for (int pan = 0; pan < 2; ++pan) {
                u16x8 af[4], bq[4];
#pragma unroll
                for (int f = 0; f < 4; ++f)
                    af[f] = *(const u16x8*)(St + pan * 8192 + (wr * 4 + f) * 512 + lane * 8);
#pragma unroll
                for (int f = 0; f < 4; ++f)
                    bq[f] = *(const u16x8*)(St + pan * 8192 + 4096 + (wc * 4 + f) * 512 + lane * 8);
#pragma unroll
                for (int fi = 0; fi < 4; ++fi)
#pragma unroll
                    for (int fj = 0; fj < 4; ++fj)
                        acc[fi][fj] = mfma16(af[fi], bq[fj], acc[fi][fj]);
            }
            __syncthreads();
        }
#pragma unroll
        for (int fi = 0; fi < 4; ++fi)
#pragma unroll
            for (int fj = 0; fj < 4; ++fj)
#pragma unroll
                for (int r = 0; r < 4; ++r) {
                    int n = i0 + wr * 64 + fi * 16 + q * 4 + r;
                    int c = j0 + wc * 64 + fj * 16 + lrow;
                    MallC_out[(size_t)n * 2048 + (2 * s + 1) * 512 + c] = f2bf(acc[fi][fj][r]);
                }
    }
}

// ---------------------------------------------------------------------------
// ysum: barrier-free. bid -> kq = bid&3 (K quarter), rt = bid>>2 (128-r tile):
// b = rt>>2, n0 = (rt&3)*128. Wave wid owns 32 r-rows. Wave tile 32r x 64o.
// Yh[kq][r][o] = sum_{m in quarter} G[n][kq*512+m] * Z[(b*64+o)][kq*512+m]
// K=512, 16 steps of BK=32, 1-step register pipeline, direct global loads.
// ---------------------------------------------------------------------------
__global__ __launch_bounds__(256) void ysum(
    const u16* __restrict__ G, const u16* __restrict__ Z, float* __restrict__ Yh)
{
    const int tid = threadIdx.x, lane = tid & 63, wid = tid >> 6;
    const int lrow = lane & 15, lk8 = (lane >> 4) * 8;
    const int q = lane >> 4;
    const int bid = blockIdx.x;
    const int kq = bid & 3, rt = bid >> 2;
    const int b = rt >> 2, n0 = (rt & 3) * 128;
    const int r0 = b * 512 + n0;

    const u16* ap[2];
#pragma unroll
    for (int fi = 0; fi < 2; ++fi)
        ap[fi] = G + (size_t)(n0 + wid * 32 + fi * 16 + lrow) * 2048 + kq * 512 + lk8;
    const u16* bp[4];
#pragma unroll
    for (int fj = 0; fj < 4; ++fj)
        bp[fj] = Z + (size_t)(b * 64 + fj * 16 + lrow) * 2048 + kq * 512 + lk8;

    u16x8 Ar[2], Br[4];
#pragma unroll
    for (int fi = 0; fi < 2; ++fi) Ar[fi] = *(const u16x8*)(ap[fi]);
#pragma unroll
    for (int fj = 0; fj < 4; ++fj) Br[fj] = *(const u16x8*)(bp[fj]);

    f32x4 acc[2][4] = {};
#pragma unroll
    for (int kk = 0; kk < 16; ++kk) {
        u16x8 Ac[2], Bc[4];
#pragma unroll
        for (int fi = 0; fi < 2; ++fi) Ac[fi] = Ar[fi];
#pragma unroll
        for (int fj = 0; fj < 4; ++fj) Bc[fj] = Br[fj];
        if (kk < 15) {
            const int d = (kk + 1) * 32;
#pragma unroll
            for (int fi = 0; fi < 2; ++fi) Ar[fi] = *(const u16x8*)(ap[fi] + d);
#pragma unroll
            for (int fj = 0; fj < 4; ++fj) Br[fj] = *(const u16x8*)(bp[fj] + d);
        }
#pragma unroll
        for (int fi = 0; fi < 2; ++fi)
#pragma unroll
            for (int fj = 0; fj < 4; ++fj)
                acc[fi][fj] = mfma16(Ac[fi], Bc[fj], acc[fi][fj]);
    }
    float* Yk = Yh + (size_t)kq * R_ * 64;
#pragma unroll
    for (int fi = 0; fi < 2; ++fi)
#pragma unroll
        for (int fj = 0; fj < 4; ++fj)
#pragma unroll
            for (int r = 0; r < 4; ++r) {
                int rr = r0 + wid * 32 + fi * 16 + q * 4 + r;
                int o  = fj * 16 + lrow;
                Yk[(size_t)rr * 64 + o] = acc[fi][fj][r];
            }
}

// ---------------------------------------------------------------------------
// bn_part: grid 256, block j: rows j*64..+63, v = sum of 4 Yh quarters.
// ---------------------------------------------------------------------------
__global__ __launch_bounds__(256) void bn_part(
    const float* __restrict__ Yh, float* __restrict__ part)
{
    const int blk = blockIdx.x, tid = threadIdx.x;
    const int o = tid & 63, g = tid >> 6;
    float s = 0.f, s2 = 0.f;
#pragma unroll
    for (int p = 0; p < 16; ++p) {
        int r = blk * 64 + p * 4 + g;
        size_t off = (size_t)r * 64 + o;
        float v = Yh[off] + Yh[(size_t)R_ * 64 + off]
                + Yh[(size_t)2 * R_ * 64 + off] + Yh[(size_t)3 * R_ * 64 + off];
        s += v; s2 += v * v;
    }
    __shared__ float ls[4][64], ls2[4][64];
    ls[g][o] = s; ls2[g][o] = s2;
    __syncthreads();
    if (tid < 64) {
        float t = 0.f, t2 = 0.f;
#pragma unroll
        for (int g2 = 0; g2 < 4; ++g2) { t += ls[g2][tid]; t2 += ls2[g2][tid]; }
        part[blk * 128 + tid]      = t;
        part[blk * 128 + 64 + tid] = t2;
    }
}

// bn_final: stats[o] = scale, stats[64+o] = shift
__global__ __launch_bounds__(256) void bn_final(
    const float* __restrict__ part, const float* __restrict__ gamma,
    const float* __restrict__ beta, float* __restrict__ stats)
{
    const int tid = threadIdx.x;
    const int c = tid & 63, g = tid >> 6;
    float s = 0.f, s2 = 0.f;
    for (int b = g; b < 256; b += 4) {
        s  += part[b * 128 + c];
        s2 += part[b * 128 + 64 + c];
    }
    __shared__ float ls[4][64], ls2[4][64];
    ls[g][c] = s; ls2[g][c] = s2;
    __syncthreads();
    if (tid < 64) {
        float t = 0.f, t2 = 0.f;
#pragma unroll
        for (int g2 = 0; g2 < 4; ++g2) { t += ls[g2][tid]; t2 += ls2[g2][tid]; }
        float mean = t * (1.0f / R_);
        float var  = t2 * (1.0f / R_) - mean * mean;
        float a = rsqrtf(var + 1e-5f) * gamma[tid];
        stats[tid]      = a;
        stats[64 + tid] = beta[tid] - mean * a;
    }
}

// ---------------------------------------------------------------------------
// bn_out: out[r][o] = sum_c relu(v[r][c]*a[c]+sh[c]) * w2[o][c] + b2[o]
// v = sum of 4 Yh quarters. grid 256 blocks of 64 rows.
// ---------------------------------------------------------------------------
__global__ __launch_bounds__(256) void bn_out(
    const float* __restrict__ Yh, const float* __restrict__ stats,
    const float* __restrict__ w2, const float* __restrict__ b2,
    float* __restrict__ out)
{
    __shared__ float ys[64 * 68];
    __shared__ float w2s[64 * 65];
    __shared__ float sa[64], sh[64];
    const int tid = threadIdx.x;
    const int r0 = blockIdx.x * 64;
#pragma unroll
    for (int i = 0; i < 16; ++i) {
        int idx = tid + i * 256;
        w2s[(idx >> 6) * 65 + (idx & 63)] = w2[idx];
    }
    if (tid < 64) { sa[tid] = stats[tid]; sh[tid] = stats[64 + tid]; }
    __syncthreads();
    const int o = tid & 63, g = tid >> 6;
    {
        float a = sa[o], bsh = sh[o];
#pragma unroll
        for (int p = 0; p < 16; ++p) {
            int rl = p * 4 + g;
            size_t off = (size_t)(r0 + rl) * 64 + o;
            float v = Yh[off] + Yh[(size_t)R_ * 64 + off]
                    + Yh[(size_t)2 * R_ * 64 + off] + Yh[(size_t)3 * R_ * 64 + off];
            ys[o * 68 + rl] = fmaxf(fmaf(v, a, bsh), 0.f);
        }
    }
    __syncthreads();
    float acc[16];
    float bb = b2[o];
#pragma unroll
    for (int j = 0; j < 16; ++j) acc[j] = bb;
    for (int c = 0; c < 64; ++c) {
        float wv = w2s[o * 65 + c];
        const float* yr = ys + c * 68 + g * 16;
        f32x4 y0 = *(const f32x4*)(yr);
        f32x4 y1 = *(const f32x4*)(yr + 4);
        f32x4 y2 = *(const f32x4*)(yr + 8);
        f32x4 y3 = *(const f32x4*)(yr + 12);
#pragma unroll
        for (int j = 0; j < 4; ++j) {
            acc[j]      = fmaf(wv, y0[j], acc[j]);
            acc[4 + j]  = fmaf(wv, y1[j], acc[4 + j]);
            acc[8 + j]  = fmaf(wv, y2[j], acc[8 + j]);
            acc[12 + j] = fmaf(wv, y3[j], acc[12 + j]);
        }
    }
#pragma unroll
    for (int j = 0; j < 16; ++j)
        out[(size_t)(r0 + g * 16 + j) * OUT_ + o] = acc[j];
}

// ---------------------------------------------------------------------------
extern "C" void kernel_launch(void* const* d_in, const int* in_sizes, int n_in,
                              void* d_out, int out_size, void* d_ws, size_t ws_size,
                              hipStream_t stream)
{
    const float* x       = (const float*)d_in[0];
    const float* support = (const float*)d_in[1];
    const float* weight  = (const float*)d_in[2];
    const float* eps     = (const float*)d_in[3];
    const float* gamma   = (const float*)d_in[4];
    const float* beta    = (const float*)d_in[5];
    const float* w2      = (const float*)d_in[6];
    const float* b2      = (const float*)d_in[7];
    float* out = (float*)d_out;

    char* ws = (char*)d_ws;
    u16*   MallC = (u16*)(ws);                      //  2,097,152  [512][2048]
    u16*   MT    = (u16*)(ws + 2097152);            //  1,048,576
    u16*   Wt    = (u16*)(ws + 3145728);            //    393,216  [256][768]
    u16*   Z     = (u16*)(ws + 3538944);            //  8,388,608  [2048][2048]
    float* Yh    = (float*)(ws + 11927552);         // 16,777,216  (4 quarters)
    float* part  = (float*)(ws + 28704768);         //    131,072
    float* stats = (float*)(ws + 28835840);         //        512

    prep2   <<<1280, 256, 0, stream>>>(support, weight, eps, MallC, MT, Wt);
    zmsq    <<<544,  256, 0, stream>>>(Wt, x, MallC, MT, Z, MallC);
    ysum    <<<512,  256, 0, stream>>>(MallC, Z, Yh);
    bn_part <<<256,  256, 0, stream>>>(Yh, part);
    bn_final<<<1,    256, 0, stream>>>(part, gamma, beta, stats);
    bn_out  <<<256,  256, 0, stream>>>(Yh, stats, w2, b2, out);
}